// Round 16
// baseline (221.709 us; speedup 1.0000x reference)
//
#include <hip/hip_runtime.h>

#define VOCAB 128
#define EMB   8
#define HID   32
#define BATCH 512
#define SEQ   512
#define G4    128   // 4*HID
#define KB    8     // recurrence steps per phase

#define LOG2E 1.4426950408889634f

typedef float v2f __attribute__((ext_vector_type(2)));

// ---------------------------------------------------------------------------
// Kernel 1: proj[v][r] = (dot(emb[v], w_ih[r]) + b_ih[r] + b_hh[r]) * rowscale
// rowscale folds exp->exp2: g-rows [64,96): 2*log2e ; others: log2e
// ---------------------------------------------------------------------------
__global__ void build_proj(const float* __restrict__ emb,
                           const float* __restrict__ w_ih,
                           const float* __restrict__ b_ih,
                           const float* __restrict__ b_hh,
                           float* __restrict__ proj) {
    int idx = blockIdx.x * blockDim.x + threadIdx.x;   // 0 .. 16383
    int v = idx >> 7;
    int r = idx & 127;
    float acc = b_ih[r] + b_hh[r];
#pragma unroll
    for (int e = 0; e < EMB; ++e)
        acc += emb[v * EMB + e] * w_ih[r * EMB + e];
    float sc = (r >= 64 && r < 96) ? (2.0f * LOG2E) : LOG2E;
    proj[v * G4 + r] = acc * sc;
}

// ---------------------------------------------------------------------------
// Fast gate nonlinearities (inputs pre-scaled by log2e / 2*log2e). Proven R10.
// ---------------------------------------------------------------------------
__device__ __forceinline__ float sig2(float x) {
    return __builtin_amdgcn_rcpf(1.0f + __builtin_amdgcn_exp2f(-x));
}
__device__ __forceinline__ float tanh2(float x2) {
    return 1.0f - 2.0f * __builtin_amdgcn_rcpf(__builtin_amdgcn_exp2f(x2) + 1.0f);
}

// ---------------------------------------------------------------------------
// Alias-proof half-broadcast (proven R10).
// ---------------------------------------------------------------------------
__device__ __forceinline__ void half_bcast(float acc, float& lo, float& hi) {
    asm("v_mov_b32 %0, %2\n\t"
        "v_mov_b32 %1, %2\n\t"
        "v_permlane32_swap_b32 %0, %1"
        : "=&v"(lo), "=&v"(hi)
        : "v"(acc));
}

// ---------------------------------------------------------------------------
// Kernel 2: FUSED LSTM recurrence + vocab projection. One sequence per wave.
// R15-proven structure. SINGLE CONCEPTUAL DELTA: the logits for position k-1
// are computed inside step k from the SAME hup[] broadcast the matvec uses
// (h_{k-1}), using per-lane-pinned w_out rows (vocab lane and lane+64).
// These FMAs are independent of the serial h->c->h chain and fill its stall
// cycles. Eliminates the out_proj kernel and all hbuf traffic.
// ---------------------------------------------------------------------------
__global__ __launch_bounds__(64)
__attribute__((amdgpu_waves_per_eu(1, 1)))
void lstm_fused(
    const int*   __restrict__ tokens,   // [B][T]
    const float* __restrict__ w_hh,     // [128][32]
    const float* __restrict__ proj,     // [128][128], pre-scaled
    const float* __restrict__ w_out,    // [128][32]
    const float* __restrict__ b_out,    // [128]
    float*       __restrict__ out)      // [B*T][128]
{
    const int b    = blockIdx.x;
    const int lane = threadIdx.x;      // 0..63

    __shared__ float sproj[VOCAB * G4];   // 64 KB

    // ---- stage proj into LDS (once) ----
    {
        const float4* src = (const float4*)proj;
        float4*       dst = (float4*)sproj;
#pragma unroll 4
        for (int i = 0; i < (VOCAB * G4 / 4) / 64; ++i)
            dst[i * 64 + lane] = src[i * 64 + lane];
    }

    // ---- recurrent weights as float2 pairs, pre-scaled, pinned (R15) ----
    const float sc1 = (lane < 32) ? (2.0f * LOG2E) : LOG2E;
    v2f w0p[HID / 2], w1p[HID / 2];
#pragma unroll
    for (int p = 0; p < HID / 2; ++p) {
        w0p[p][0] = w_hh[lane * HID + 2 * p]     * LOG2E;
        w0p[p][1] = w_hh[lane * HID + 2 * p + 1] * LOG2E;
        w1p[p][0] = w_hh[(lane + 64) * HID + 2 * p]     * sc1;
        w1p[p][1] = w_hh[(lane + 64) * HID + 2 * p + 1] * sc1;
    }
#pragma unroll
    for (int p = 0; p < HID / 2; ++p) {
        asm volatile("" : "+v"(w0p[p]), "+v"(w1p[p]));
    }

    // ---- output weights for this lane's two vocab entries, pinned ----
    v2f wop0[HID / 2], wop1[HID / 2];
#pragma unroll
    for (int p = 0; p < HID / 2; ++p) {
        wop0[p][0] = w_out[lane * HID + 2 * p];
        wop0[p][1] = w_out[lane * HID + 2 * p + 1];
        wop1[p][0] = w_out[(lane + 64) * HID + 2 * p];
        wop1[p][1] = w_out[(lane + 64) * HID + 2 * p + 1];
    }
#pragma unroll
    for (int p = 0; p < HID / 2; ++p) {
        asm volatile("" : "+v"(wop0[p]), "+v"(wop1[p]));
    }
    const float bb0 = b_out[lane];
    const float bb1 = b_out[lane + 64];

    // ---- all 512 tokens of this sequence in lane registers ----
    const int* tok = tokens + b * SEQ;
    int tv[KB];
    {
        int4 a = ((const int4*)tok)[lane * 2];
        int4 d = ((const int4*)tok)[lane * 2 + 1];
        tv[0] = a.x; tv[1] = a.y; tv[2] = a.z; tv[3] = a.w;
        tv[4] = d.x; tv[5] = d.y; tv[6] = d.z; tv[7] = d.w;
    }

    __syncthreads();

    float h = 0.0f, c = 0.0f;
    float* op = out + (size_t)b * SEQ * VOCAB;   // this sequence's logits
    float lsave0[KB], lsave1[KB];

    // xp double buffer in registers
    float xc0[KB], xc1[KB];
#pragma unroll
    for (int k = 0; k < KB; ++k) {
        int tk = __builtin_amdgcn_readlane(tv[k], 0);
        xc0[k] = sproj[tk * G4 + lane];
        xc1[k] = sproj[tk * G4 + 64 + lane];
    }

    for (int t0 = 0; t0 < SEQ; t0 += KB) {
        // ---- phase A: issue next block's 16 ds_reads ----
        const int nb = t0 + KB;
        const int ln = (nb < SEQ) ? (nb >> 3) : 0;
        float xn0[KB], xn1[KB];
#pragma unroll
        for (int k = 0; k < KB; ++k) {
            int tk = __builtin_amdgcn_readlane(tv[k], ln);
            xn0[k] = sproj[tk * G4 + lane];
            xn1[k] = sproj[tk * G4 + 64 + lane];
        }
        __builtin_amdgcn_sched_barrier(0);

        // ---- phase B: 8 recurrence steps + fused logits of prev step ----
#pragma unroll
        for (int k = 0; k < KB; ++k) {
            // broadcast h_{step-1} once; feeds BOTH matvec and logits
            unsigned hb = __float_as_uint(h);
            v2f hup[HID / 2];
#pragma unroll
            for (int p = 0; p < HID / 2; ++p) {
                hup[p][0] = __uint_as_float(__builtin_amdgcn_readlane(hb, 2 * p));
                hup[p][1] = __uint_as_float(__builtin_amdgcn_readlane(hb, 2 * p + 1));
            }
            __builtin_amdgcn_sched_barrier(0);

            // fused logits for position (t0+k-1): independent of the chain
            {
                v2f lA = {0.0f, 0.0f}, lB = {0.0f, 0.0f},
                    lC = {0.0f, 0.0f}, lD = {0.0f, 0.0f};
                v2f mA = {0.0f, 0.0f}, mB = {0.0f, 0.0f},
                    mC = {0.0f, 0.0f}, mD = {0.0f, 0.0f};
#pragma unroll
                for (int p = 0; p < HID / 2; p += 4) {
                    lA = __builtin_elementwise_fma(hup[p],     wop0[p],     lA);
                    lB = __builtin_elementwise_fma(hup[p + 1], wop0[p + 1], lB);
                    lC = __builtin_elementwise_fma(hup[p + 2], wop0[p + 2], lC);
                    lD = __builtin_elementwise_fma(hup[p + 3], wop0[p + 3], lD);
                    mA = __builtin_elementwise_fma(hup[p],     wop1[p],     mA);
                    mB = __builtin_elementwise_fma(hup[p + 1], wop1[p + 1], mB);
                    mC = __builtin_elementwise_fma(hup[p + 2], wop1[p + 2], mC);
                    mD = __builtin_elementwise_fma(hup[p + 3], wop1[p + 3], mD);
                }
                v2f lS = (lA + lB) + (lC + lD);
                v2f mS = (mA + mB) + (mC + mD);
                lsave0[k] = lS[0] + lS[1] + bb0;
                lsave1[k] = mS[0] + mS[1] + bb1;
            }

            // packed matvec (R15-proven)
            v2f sA = {xc0[k], 0.0f}, sB = {0.0f, 0.0f},
                sC = {0.0f, 0.0f},   sD = {0.0f, 0.0f};
            v2f uA = {xc1[k], 0.0f}, uB = {0.0f, 0.0f},
                uC = {0.0f, 0.0f},   uD = {0.0f, 0.0f};
#pragma unroll
            for (int p = 0; p < HID / 2; p += 4) {
                sA = __builtin_elementwise_fma(hup[p],     w0p[p],     sA);
                sB = __builtin_elementwise_fma(hup[p + 1], w0p[p + 1], sB);
                sC = __builtin_elementwise_fma(hup[p + 2], w0p[p + 2], sC);
                sD = __builtin_elementwise_fma(hup[p + 3], w0p[p + 3], sD);
                uA = __builtin_elementwise_fma(hup[p],     w1p[p],     uA);
                uB = __builtin_elementwise_fma(hup[p + 1], w1p[p + 1], uB);
                uC = __builtin_elementwise_fma(hup[p + 2], w1p[p + 2], uC);
                uD = __builtin_elementwise_fma(hup[p + 3], w1p[p + 3], uD);
            }
            v2f sS = (sA + sB) + (sC + sD);
            v2f uS = (uA + uB) + (uC + uD);
            float acc0 = sS[0] + sS[1];   // i (lo lanes) | f (hi lanes)
            float acc1 = uS[0] + uS[1];   // g (lo, *2log2e) | o (hi)

            float iv, fv, gv, ov;
            half_bcast(acc0, iv, fv);
            half_bcast(acc1, gv, ov);

            c = sig2(fv) * c + sig2(iv) * tanh2(gv);
            h = sig2(ov) * tanh2(c * (2.0f * LOG2E));

            xc0[k] = 0.0f;  // dead; rotated in phase D
        }

        // ---- phase C: flush logit stores for positions t0-1 .. t0+6 ----
#pragma unroll
        for (int k = 0; k < KB; ++k) {
            const int p = t0 + k - 1;
            if (p >= 0) {
                op[(size_t)p * VOCAB + lane]      = lsave0[k];
                op[(size_t)p * VOCAB + 64 + lane] = lsave1[k];
            }
        }

        // ---- phase D: rotate next block into current ----
#pragma unroll
        for (int k = 0; k < KB; ++k) {
            xc0[k] = xn0[k];
            xc1[k] = xn1[k];
        }
    }

    // ---- epilogue: logits for final position (SEQ-1) from final h ----
    {
        unsigned hb = __float_as_uint(h);
        v2f hup[HID / 2];
#pragma unroll
        for (int p = 0; p < HID / 2; ++p) {
            hup[p][0] = __uint_as_float(__builtin_amdgcn_readlane(hb, 2 * p));
            hup[p][1] = __uint_as_float(__builtin_amdgcn_readlane(hb, 2 * p + 1));
        }
        v2f lA = {0.0f, 0.0f}, lB = {0.0f, 0.0f},
            lC = {0.0f, 0.0f}, lD = {0.0f, 0.0f};
        v2f mA = {0.0f, 0.0f}, mB = {0.0f, 0.0f},
            mC = {0.0f, 0.0f}, mD = {0.0f, 0.0f};
#pragma unroll
        for (int p = 0; p < HID / 2; p += 4) {
            lA = __builtin_elementwise_fma(hup[p],     wop0[p],     lA);
            lB = __builtin_elementwise_fma(hup[p + 1], wop0[p + 1], lB);
            lC = __builtin_elementwise_fma(hup[p + 2], wop0[p + 2], lC);
            lD = __builtin_elementwise_fma(hup[p + 3], wop0[p + 3], lD);
            mA = __builtin_elementwise_fma(hup[p],     wop1[p],     mA);
            mB = __builtin_elementwise_fma(hup[p + 1], wop1[p + 1], mB);
            mC = __builtin_elementwise_fma(hup[p + 2], wop1[p + 2], mC);
            mD = __builtin_elementwise_fma(hup[p + 3], wop1[p + 3], mD);
        }
        v2f lS = (lA + lB) + (lC + lD);
        v2f mS = (mA + mB) + (mC + mD);
        op[(size_t)(SEQ - 1) * VOCAB + lane]      = lS[0] + lS[1] + bb0;
        op[(size_t)(SEQ - 1) * VOCAB + 64 + lane] = mS[0] + mS[1] + bb1;
    }
}

// ---------------------------------------------------------------------------
extern "C" void kernel_launch(void* const* d_in, const int* in_sizes, int n_in,
                              void* d_out, int out_size, void* d_ws, size_t ws_size,
                              hipStream_t stream) {
    const int*   tokens = (const int*)  d_in[0];
    const float* emb    = (const float*)d_in[1];
    const float* w_ih   = (const float*)d_in[2];
    const float* w_hh   = (const float*)d_in[3];
    const float* b_ih   = (const float*)d_in[4];
    const float* b_hh   = (const float*)d_in[5];
    const float* w_out  = (const float*)d_in[6];
    const float* b_out  = (const float*)d_in[7];
    float*       out    = (float*)d_out;

    float* proj = (float*)d_ws;

    build_proj<<<(VOCAB * G4) / 256, 256, 0, stream>>>(emb, w_ih, b_ih, b_hh, proj);

    lstm_fused<<<BATCH, 64, 0, stream>>>(tokens, w_hh, proj, w_out, b_out, out);
}